// Round 4
// baseline (91.748 us; speedup 1.0000x reference)
//
#include <hip/hip_runtime.h>
#include <stdint.h>

using bf16x8_t = __attribute__((ext_vector_type(8))) __bf16;
using f32x4_t  = __attribute__((ext_vector_type(4))) float;
using u16x8_t  = __attribute__((ext_vector_type(8))) unsigned short;

#define KD 2048

static __device__ __forceinline__ unsigned short f2bf(float f) {
  union { float f; unsigned u; } v; v.f = f;
  unsigned r = v.u + 0x7fffu + ((v.u >> 16) & 1u);   // RNE
  return (unsigned short)(r >> 16);
}

// ---- prep1: partial[b][h] = sum over 10 W-rows (qkv||z), deterministic ----
__global__ void k_prep1(const float* __restrict__ wqkv, const float* __restrict__ wz,
                        float* __restrict__ partial) {
  const int b = blockIdx.x, t = threadIdx.x;     // 128 blocks x 256 thr
  float p[8] = {0.f,0.f,0.f,0.f,0.f,0.f,0.f,0.f};
  #pragma unroll
  for (int dd = 0; dd < 10; ++dd) {
    const int d = b * 10 + dd;                   // 0..1279
    const float* row = (d < 768) ? (wqkv + (size_t)d * KD)
                                 : (wz + (size_t)(d - 768) * KD);
    #pragma unroll
    for (int j = 0; j < 8; ++j) p[j] += row[t + 256 * j];
  }
  #pragma unroll
  for (int j = 0; j < 8; ++j) partial[(size_t)b * KD + t + 256 * j] = p[j];
}

// ---- prep2: pack 9-fragment bf16 W. Layout: elem ((s*9+nf)*64+lane)*8+j  <->
//  B[col = nf*16+(lane&15)][k = s*32+(lane>>4)*8+j]; cols 0..63 = w_a rows,
//  64..127 = w_b rows, col 128 = wsum (from partial), cols 129..143 = 0. ----
__global__ void k_prep2(const float* __restrict__ wb, const float* __restrict__ wa,
                        const float* __restrict__ partial, unsigned short* __restrict__ wbf3) {
  const int u = blockIdx.x * 256 + threadIdx.x;  // 144 blocks -> 36864 threads
  const int l = u & 63;
  const int vv = u >> 6;
  const int nf = vv % 9;
  const int s  = vv / 9;
  const int k  = s * 32 + ((l >> 4) << 3);
  u16x8_t o;
  if (nf < 8) {
    const int c = nf * 16 + (l & 15);
    const float* src = (c < 64) ? (wa + (size_t)c * KD + k)
                                : (wb + (size_t)(c - 64) * KD + k);
    f32x4_t v0 = *(const f32x4_t*)(src);
    f32x4_t v1 = *(const f32x4_t*)(src + 4);
    o[0]=f2bf(v0[0]); o[1]=f2bf(v0[1]); o[2]=f2bf(v0[2]); o[3]=f2bf(v0[3]);
    o[4]=f2bf(v1[0]); o[5]=f2bf(v1[1]); o[6]=f2bf(v1[2]); o[7]=f2bf(v1[3]);
  } else if ((l & 15) == 0) {
    f32x4_t s0 = {0.f,0.f,0.f,0.f}, s1 = {0.f,0.f,0.f,0.f};
    for (int p = 0; p < 128; ++p) {
      s0 += *(const f32x4_t*)(partial + (size_t)p * KD + k);
      s1 += *(const f32x4_t*)(partial + (size_t)p * KD + k + 4);
    }
    o[0]=f2bf(s0[0]); o[1]=f2bf(s0[1]); o[2]=f2bf(s0[2]); o[3]=f2bf(s0[3]);
    o[4]=f2bf(s1[0]); o[5]=f2bf(s1[1]); o[6]=f2bf(s1[2]); o[7]=f2bf(s1[3]);
  } else {
    o[0]=0; o[1]=0; o[2]=0; o[3]=0; o[4]=0; o[5]=0; o[6]=0; o[7]=0;
  }
  *(u16x8_t*)(wbf3 + (size_t)u * 8) = o;
}

// ---- main: BM=64 (4 waves x 16 rows), BK=64, N=144 (9 frags).
// LDS = 2 x 18KB double buffer -> 4 blocks/CU (16 waves) for TLP across
// barrier drains. A: global->reg nontemporal, fp32->bf16 via native cvt.
// B: global_load_lds(16B) from pre-fragmented wbf3. s0 folded into MFMA (acc[8]).
__global__ __launch_bounds__(256, 4) void k_main(
    const float* __restrict__ x, const unsigned short* __restrict__ wbf3,
    float* __restrict__ out)
{
  __shared__ __align__(16) unsigned char lds[2 * 18432];   // 36 KB
  const int t = threadIdx.x;
  const int lane = t & 63;
  const int wv = t >> 6;
  const int g = lane >> 4;
  const int r15 = lane & 15;
  const size_t tile = (size_t)blockIdx.x * 64;

  const float* xrow = x + (tile + wv * 16 + r15) * KD + g * 8;

  f32x4_t acc[9];
  #pragma unroll
  for (int i = 0; i < 9; ++i) acc[i] = f32x4_t{0.f, 0.f, 0.f, 0.f};

  // stage one BK=64 tile (18 KB = 18 chunks of 1KB; waves 0,1 take 5, waves 2,3 take 4)
  auto STAGE = [&](int it, int bsel) {
    unsigned char* bp = lds + bsel * 18432;
    const unsigned short* gp = wbf3 + (size_t)it * 9216 + lane * 8;
    #pragma unroll
    for (int c = 0; c < 5; ++c) {
      const int ch = wv + c * 4;
      if (ch < 18)
        __builtin_amdgcn_global_load_lds(
            (const __attribute__((address_space(1))) void*)(gp + ch * 512),
            (__attribute__((address_space(3))) void*)(bp + ch * 1024), 16, 0, 0);
    }
  };
  auto XLOAD = [&](int it, f32x4_t* xv) {
    const float* p = xrow + it * 64;
    #pragma unroll
    for (int ss = 0; ss < 2; ++ss) {
      xv[2*ss]   = __builtin_nontemporal_load((const f32x4_t*)(p + ss * 32));
      xv[2*ss+1] = __builtin_nontemporal_load((const f32x4_t*)(p + ss * 32 + 4));
    }
  };
  auto COMPUTE = [&](int bsel, const f32x4_t* xv) {
    const unsigned char* bp = lds + bsel * 18432;
    #pragma unroll
    for (int ss = 0; ss < 2; ++ss) {
      f32x4_t x0 = xv[2*ss], x1 = xv[2*ss+1];
      bf16x8_t af;
      af[0] = (__bf16)x0[0]; af[1] = (__bf16)x0[1];
      af[2] = (__bf16)x0[2]; af[3] = (__bf16)x0[3];
      af[4] = (__bf16)x1[0]; af[5] = (__bf16)x1[1];
      af[6] = (__bf16)x1[2]; af[7] = (__bf16)x1[3];
      #pragma unroll
      for (int nf = 0; nf < 9; ++nf) {
        bf16x8_t bfr = *(const bf16x8_t*)(bp + ((ss * 9 + nf) * 64 + lane) * 16);
        acc[nf] = __builtin_amdgcn_mfma_f32_16x16x32_bf16(af, bfr, acc[nf], 0, 0, 0);
      }
    }
  };

  f32x4_t xA[4], xB[4];
  STAGE(0, 0);
  XLOAD(0, xA);
  __syncthreads();

  for (int it = 0; it < 32; it += 2) {
    STAGE(it + 1, 1);
    XLOAD(it + 1, xB);
    COMPUTE(0, xA);
    __syncthreads();
    if (it + 2 < 32) { STAGE(it + 2, 0); XLOAD(it + 2, xA); }
    COMPUTE(1, xB);
    __syncthreads();
  }

  // epilogue: C col=lane&15, row=g*4+reg. a-frag nf pairs with b-frag nf+4.
  // acc[8][r] (col 128) = qkv+z fold, already at the writer lane (r15==0).
  #pragma unroll
  for (int r = 0; r < 4; ++r) {
    float v = 0.f;
    #pragma unroll
    for (int nf = 0; nf < 4; ++nf) {
      float av = acc[nf][r];
      float bv = acc[nf + 4][r];
      v += av / (1.f + __expf(-bv));          // a * sigmoid(b)
    }
    v += __shfl_xor(v, 1, 64);
    v += __shfl_xor(v, 2, 64);
    v += __shfl_xor(v, 4, 64);
    v += __shfl_xor(v, 8, 64);
    if (r15 == 0) out[tile + wv * 16 + g * 4 + r] = v + acc[8][r];
  }
}

extern "C" void kernel_launch(void* const* d_in, const int* in_sizes, int n_in,
                              void* d_out, int out_size, void* d_ws, size_t ws_size,
                              hipStream_t stream) {
  const float* x    = (const float*)d_in[0];
  const float* wqkv = (const float*)d_in[1];
  const float* wz   = (const float*)d_in[2];
  const float* wb   = (const float*)d_in[3];   // dict order: w_b before w_a
  const float* wa   = (const float*)d_in[4];
  float* out = (float*)d_out;

  float* partial = (float*)d_ws;                                     // 128*2048 f32 = 1 MB
  unsigned short* wbf3 = (unsigned short*)((char*)d_ws + (1 << 20)); // 576 KB pre-fragmented W

  k_prep1<<<128, 256, 0, stream>>>(wqkv, wz, partial);
  k_prep2<<<144, 256, 0, stream>>>(wb, wa, partial, wbf3);
  k_main<<<out_size / 64, 256, 0, stream>>>(x, wbf3, out);
}

// Round 5
// 80.232 us; speedup vs baseline: 1.1435x; 1.1435x over previous
//
#include <hip/hip_runtime.h>
#include <stdint.h>

using bf16x8_t = __attribute__((ext_vector_type(8))) __bf16;
using f32x4_t  = __attribute__((ext_vector_type(4))) float;
using u16x8_t  = __attribute__((ext_vector_type(8))) unsigned short;

#define KD 2048

static __device__ __forceinline__ unsigned short f2bf(float f) {
  union { float f; unsigned u; } v; v.f = f;
  unsigned r = v.u + 0x7fffu + ((v.u >> 16) & 1u);   // RNE
  return (unsigned short)(r >> 16);
}

// ---- prep1: partial[b][h] = sum over 10 W-rows (qkv||z), deterministic ----
__global__ void k_prep1(const float* __restrict__ wqkv, const float* __restrict__ wz,
                        float* __restrict__ partial) {
  const int b = blockIdx.x, t = threadIdx.x;     // 128 blocks x 256 thr
  float p[8] = {0.f,0.f,0.f,0.f,0.f,0.f,0.f,0.f};
  #pragma unroll
  for (int dd = 0; dd < 10; ++dd) {
    const int d = b * 10 + dd;                   // 0..1279
    const float* row = (d < 768) ? (wqkv + (size_t)d * KD)
                                 : (wz + (size_t)(d - 768) * KD);
    #pragma unroll
    for (int j = 0; j < 8; ++j) p[j] += row[t + 256 * j];
  }
  #pragma unroll
  for (int j = 0; j < 8; ++j) partial[(size_t)b * KD + t + 256 * j] = p[j];
}

// ---- wsum2: wsum[h] = sum_p partial[p][h], coalesced column reduction ----
__global__ void k_wsum2(const float* __restrict__ partial, float* __restrict__ wsum) {
  const int h = blockIdx.x * 256 + threadIdx.x;  // 8 blocks
  float s = 0.f;
  #pragma unroll 8
  for (int p = 0; p < 128; ++p) s += partial[(size_t)p * KD + h];
  wsum[h] = s;
}

// ---- prep2: pack 8-fragment bf16 W. elem ((s*8+nf)*64+lane)*8+j  <->
//  B[col = nf*16+(lane&15)][k = s*32+(lane>>4)*8+j]; cols 0..63 = w_a rows,
//  64..127 = w_b rows. ----
__global__ void k_prep2(const float* __restrict__ wb, const float* __restrict__ wa,
                        unsigned short* __restrict__ wbf3) {
  const int u = blockIdx.x * 256 + threadIdx.x;  // 128 blocks -> 32768 threads
  const int l = u & 63;
  const int vv = u >> 6;
  const int nf = vv & 7;
  const int s  = vv >> 3;
  const int k  = s * 32 + ((l >> 4) << 3);
  const int c  = nf * 16 + (l & 15);
  const float* src = (c < 64) ? (wa + (size_t)c * KD + k)
                              : (wb + (size_t)(c - 64) * KD + k);
  f32x4_t v0 = *(const f32x4_t*)(src);
  f32x4_t v1 = *(const f32x4_t*)(src + 4);
  u16x8_t o;
  o[0]=f2bf(v0[0]); o[1]=f2bf(v0[1]); o[2]=f2bf(v0[2]); o[3]=f2bf(v0[3]);
  o[4]=f2bf(v1[0]); o[5]=f2bf(v1[1]); o[6]=f2bf(v1[2]); o[7]=f2bf(v1[3]);
  *(u16x8_t*)(wbf3 + (size_t)u * 8) = o;
}

// ---- main: BM=64 (4 waves x 16 rows), BK=64, 8 W-frags.
// ALL global x traffic via global_load_lds: each instruction reads 1KB
// CONTIGUOUS (1 page) — fixes per-lane 8KB-strided pattern (TLB/granule).
// x tile [64 rows][16 chunks of 16B], chunk-XOR-swizzled (c^=row&7) so
// A-frag ds_read_b128 is conflict-free. W tile lane-linear (conflict-free).
// s0 = fp32 VALU dot vs L1-resident wsum. LDS = 64 KB -> 2 blocks/CU.
__global__ __launch_bounds__(256, 2) void k_main(
    const float* __restrict__ x, const unsigned short* __restrict__ wbf3,
    const float* __restrict__ wsum, float* __restrict__ out)
{
  __shared__ __align__(16) unsigned char lds[65536];
  // [0, 32768): x tiles (2 x 16 KB); [32768, 65536): W tiles (2 x 16 KB)
  const int t = threadIdx.x;
  const int lane = t & 63;
  const int wv = t >> 6;
  const int g = lane >> 4;        // k-group 0..3
  const int r15 = lane & 15;
  const size_t tile = (size_t)blockIdx.x * 64;

  f32x4_t acc[8];
  #pragma unroll
  for (int i = 0; i < 8; ++i) acc[i] = f32x4_t{0.f, 0.f, 0.f, 0.f};
  float s0 = 0.f;

  auto STAGE = [&](int it, int bsel) {
    // W: 16 chunks of 1KB (2 ss x 8 nf), wave wv stages chunks wv*4..wv*4+3
    unsigned char* wbp = lds + 32768 + bsel * 16384;
    const unsigned short* gw = wbf3 + (size_t)it * 8192 + lane * 8;
    #pragma unroll
    for (int i = 0; i < 4; ++i) {
      const int ch = wv * 4 + i;
      __builtin_amdgcn_global_load_lds(
          (const __attribute__((address_space(1))) void*)(gw + ch * 512),
          (__attribute__((address_space(3))) void*)(wbp + ch * 1024), 16, 0, 0);
    }
    // X: 16 chunks of 1KB; chunk ch covers rows ch*4..ch*4+3 (256B each, contiguous)
    unsigned char* xbp = lds + bsel * 16384;
    #pragma unroll
    for (int i = 0; i < 4; ++i) {
      const int ch = wv * 4 + i;
      const int row = ch * 4 + (lane >> 4);          // row within tile
      const int c = (lane & 15) ^ (row & 7);         // source chunk (inv-swizzle)
      const float* src = x + (tile + row) * KD + it * 64 + c * 4;
      __builtin_amdgcn_global_load_lds(
          (const __attribute__((address_space(1))) void*)src,
          (__attribute__((address_space(3))) void*)(xbp + ch * 1024), 16, 0, 0);
    }
  };

  STAGE(0, 0);
  __syncthreads();

  for (int it = 0; it < 32; ++it) {
    const int cur = it & 1;
    if (it + 1 < 32) STAGE(it + 1, cur ^ 1);

    const float* wsp = wsum + it * 64 + g * 8;       // L1-hot 8KB table
    f32x4_t ws0 = *(const f32x4_t*)(wsp);
    f32x4_t ws1 = *(const f32x4_t*)(wsp + 4);
    f32x4_t ws2 = *(const f32x4_t*)(wsp + 32);
    f32x4_t ws3 = *(const f32x4_t*)(wsp + 36);

    const unsigned char* xbp = lds + cur * 16384;
    const unsigned char* wbp = lds + 32768 + cur * 16384;
    const int xrow = (wv * 16 + r15) * 256;
    const int sw = r15 & 7;

    #pragma unroll
    for (int ss = 0; ss < 2; ++ss) {
      const int c0 = ss * 8 + g * 2;
      f32x4_t lo = *(const f32x4_t*)(xbp + xrow + ((c0)     ^ sw) * 16);
      f32x4_t hi = *(const f32x4_t*)(xbp + xrow + ((c0 + 1) ^ sw) * 16);
      bf16x8_t af;
      af[0] = (__bf16)lo[0]; af[1] = (__bf16)lo[1];
      af[2] = (__bf16)lo[2]; af[3] = (__bf16)lo[3];
      af[4] = (__bf16)hi[0]; af[5] = (__bf16)hi[1];
      af[6] = (__bf16)hi[2]; af[7] = (__bf16)hi[3];
      f32x4_t wsl = ss ? ws2 : ws0;
      f32x4_t wsh = ss ? ws3 : ws1;
      s0 += lo[0]*wsl[0] + lo[1]*wsl[1] + lo[2]*wsl[2] + lo[3]*wsl[3]
          + hi[0]*wsh[0] + hi[1]*wsh[1] + hi[2]*wsh[2] + hi[3]*wsh[3];
      #pragma unroll
      for (int nf = 0; nf < 8; ++nf) {
        bf16x8_t bfr = *(const bf16x8_t*)(wbp + ((ss * 8 + nf) * 64 + lane) * 16);
        acc[nf] = __builtin_amdgcn_mfma_f32_16x16x32_bf16(af, bfr, acc[nf], 0, 0, 0);
      }
    }
    __syncthreads();
  }

  // s0: combine the 4 k-groups of each row (lanes differing in bits 4,5)
  s0 += __shfl_xor(s0, 16, 64);
  s0 += __shfl_xor(s0, 32, 64);

  // epilogue: C col=lane&15, row=g*4+reg; a-frag nf pairs with b-frag nf+4
  #pragma unroll
  for (int r = 0; r < 4; ++r) {
    float v = 0.f;
    #pragma unroll
    for (int nf = 0; nf < 4; ++nf) {
      float av = acc[nf][r];
      float bv = acc[nf + 4][r];
      v += av / (1.f + __expf(-bv));          // a * sigmoid(b)
    }
    v += __shfl_xor(v, 1, 64);
    v += __shfl_xor(v, 2, 64);
    v += __shfl_xor(v, 4, 64);
    v += __shfl_xor(v, 8, 64);
    const int row = g * 4 + r;
    float s0r = __shfl(s0, row, 64);          // s0 lives at lane with r15==row
    if (r15 == 0) out[tile + wv * 16 + row] = v + s0r;
  }
}

extern "C" void kernel_launch(void* const* d_in, const int* in_sizes, int n_in,
                              void* d_out, int out_size, void* d_ws, size_t ws_size,
                              hipStream_t stream) {
  const float* x    = (const float*)d_in[0];
  const float* wqkv = (const float*)d_in[1];
  const float* wz   = (const float*)d_in[2];
  const float* wb   = (const float*)d_in[3];   // dict order: w_b before w_a
  const float* wa   = (const float*)d_in[4];
  float* out = (float*)d_out;

  float* partial = (float*)d_ws;                                      // 1 MB
  float* wsum = (float*)((char*)d_ws + (1 << 20));                    // 8 KB
  unsigned short* wbf3 = (unsigned short*)((char*)d_ws + (1 << 20) + 8192); // 512 KB

  k_prep1<<<128, 256, 0, stream>>>(wqkv, wz, partial);
  k_wsum2<<<8, 256, 0, stream>>>(partial, wsum);
  k_prep2<<<128, 256, 0, stream>>>(wb, wa, wbf3);
  k_main<<<out_size / 64, 256, 0, stream>>>(x, wbf3, wsum, out);
}

// Round 6
// 65.766 us; speedup vs baseline: 1.3951x; 1.2200x over previous
//
#include <hip/hip_runtime.h>
#include <stdint.h>

using bf16x8_t = __attribute__((ext_vector_type(8))) __bf16;
using f32x4_t  = __attribute__((ext_vector_type(4))) float;
using u16x8_t  = __attribute__((ext_vector_type(8))) unsigned short;

#define KD 2048

static __device__ __forceinline__ unsigned short f2bf(float f) {
  union { float f; unsigned u; } v; v.f = f;
  unsigned r = v.u + 0x7fffu + ((v.u >> 16) & 1u);   // RNE
  return (unsigned short)(r >> 16);
}

// ---- prep1: partial[b][h] = sum over 10 W-rows (qkv||z), deterministic ----
__global__ void k_prep1(const float* __restrict__ wqkv, const float* __restrict__ wz,
                        float* __restrict__ partial) {
  const int b = blockIdx.x, t = threadIdx.x;     // 128 blocks x 256 thr
  float p[8] = {0.f,0.f,0.f,0.f,0.f,0.f,0.f,0.f};
  #pragma unroll
  for (int dd = 0; dd < 10; ++dd) {
    const int d = b * 10 + dd;                   // 0..1279
    const float* row = (d < 768) ? (wqkv + (size_t)d * KD)
                                 : (wz + (size_t)(d - 768) * KD);
    #pragma unroll
    for (int j = 0; j < 8; ++j) p[j] += row[t + 256 * j];
  }
  #pragma unroll
  for (int j = 0; j < 8; ++j) partial[(size_t)b * KD + t + 256 * j] = p[j];
}

// ---- wsum2: wsum[h] = sum_p partial[p][h], coalesced column reduction ----
__global__ void k_wsum2(const float* __restrict__ partial, float* __restrict__ wsum) {
  const int h = blockIdx.x * 256 + threadIdx.x;  // 8 blocks
  float s = 0.f;
  #pragma unroll 8
  for (int p = 0; p < 128; ++p) s += partial[(size_t)p * KD + h];
  wsum[h] = s;
}

// ---- prep2: pack 8-fragment bf16 W. elem ((s*8+nf)*64+lane)*8+j  <->
//  B[col = nf*16+(lane&15)][k = s*32+(lane>>4)*8+j]; cols 0..63 = w_a rows,
//  64..127 = w_b rows. ----
__global__ void k_prep2(const float* __restrict__ wb, const float* __restrict__ wa,
                        unsigned short* __restrict__ wbf3) {
  const int u = blockIdx.x * 256 + threadIdx.x;  // 128 blocks -> 32768 threads
  const int l = u & 63;
  const int vv = u >> 6;
  const int nf = vv & 7;
  const int s  = vv >> 3;
  const int k  = s * 32 + ((l >> 4) << 3);
  const int c  = nf * 16 + (l & 15);
  const float* src = (c < 64) ? (wa + (size_t)c * KD + k)
                              : (wb + (size_t)(c - 64) * KD + k);
  f32x4_t v0 = *(const f32x4_t*)(src);
  f32x4_t v1 = *(const f32x4_t*)(src + 4);
  u16x8_t o;
  o[0]=f2bf(v0[0]); o[1]=f2bf(v0[1]); o[2]=f2bf(v0[2]); o[3]=f2bf(v0[3]);
  o[4]=f2bf(v1[0]); o[5]=f2bf(v1[1]); o[6]=f2bf(v1[2]); o[7]=f2bf(v1[3]);
  *(u16x8_t*)(wbf3 + (size_t)u * 8) = o;
}

// ---- main: BM=64 (4 waves x 16 rows), BK=32, 64 K-steps.
// Counted-vmcnt pipeline (T3/T4): X triple-buffered (2-iter latency cover),
// W double-buffered (1-iter). Raw s_barrier + s_waitcnt vmcnt(2) -> loads
// stay in flight across barriers; never drain to 0 in the main loop.
// LDS: 3x8K X | 2x8K W | 8K wsum = 48 KB -> 2 blocks/CU.
// X chunks are wave-private (wave stages exactly the rows it computes).
__global__ __launch_bounds__(256, 2) void k_main(
    const float* __restrict__ x, const unsigned short* __restrict__ wbf3,
    const float* __restrict__ wsum, float* __restrict__ out)
{
  __shared__ __align__(16) unsigned char lds[49152];
  float* swb = (float*)(lds + 40960);
  const int t = threadIdx.x;
  const int lane = t & 63;
  const int wv = t >> 6;
  const int g = lane >> 4;        // k-group 0..3
  const int r15 = lane & 15;
  const size_t tile = (size_t)blockIdx.x * 64;

  // one-time: wsum -> LDS (fp32, 8 KB)
  {
    f32x4_t a = *(const f32x4_t*)(wsum + t * 8);
    f32x4_t b = *(const f32x4_t*)(wsum + t * 8 + 4);
    *(f32x4_t*)(swb + t * 8) = a;
    *(f32x4_t*)(swb + t * 8 + 4) = b;
  }
  __syncthreads();   // wsum visible; vmcnt drained -> clean counting below

  f32x4_t acc[8];
  #pragma unroll
  for (int i = 0; i < 8; ++i) acc[i] = f32x4_t{0.f, 0.f, 0.f, 0.f};
  float s0 = 0.f;

  // W stage: 8 chunks of 1KB; wave wv takes chunks wv*2, wv*2+1 (2 vmcnt units)
  auto STAGE_W = [&](int it) {
    unsigned char* wbp = lds + 24576 + (it & 1) * 8192;
    const unsigned short* gw = wbf3 + (size_t)it * 4096 + lane * 8;
    #pragma unroll
    for (int i = 0; i < 2; ++i) {
      const int ch = wv * 2 + i;
      __builtin_amdgcn_global_load_lds(
          (const __attribute__((address_space(1))) void*)(gw + ch * 512),
          (__attribute__((address_space(3))) void*)(wbp + ch * 1024), 16, 0, 0);
    }
  };
  // X stage: 8 chunks of 1KB (8 rows x 128B each); wave-private rows.
  // LDS[row][slot] holds global slot (slot ^ (row&7))  (XOR swizzle).
  auto STAGE_X = [&](int it, int bsel) {
    unsigned char* xbp = lds + bsel * 8192;
    #pragma unroll
    for (int i = 0; i < 2; ++i) {
      const int ch = wv * 2 + i;
      const int r = ch * 8 + (lane >> 3);          // row within tile
      const int c = (lane & 7) ^ (r & 7);          // source 16B slot
      const float* src = x + (tile + r) * KD + it * 32 + c * 4;
      __builtin_amdgcn_global_load_lds(
          (const __attribute__((address_space(1))) void*)src,
          (__attribute__((address_space(3))) void*)(xbp + ch * 1024), 16, 0, 0);
    }
  };
  auto COMPUTE = [&](int it, int xbsel) {
    const unsigned char* xbp = lds + xbsel * 8192;
    const unsigned char* wbp = lds + 24576 + (it & 1) * 8192;
    const float* wsp = swb + it * 32 + g * 8;      // broadcast (free)
    f32x4_t w0 = *(const f32x4_t*)(wsp);
    f32x4_t w1 = *(const f32x4_t*)(wsp + 4);
    const int r = wv * 16 + r15;
    const unsigned char* xr = xbp + r * 128;
    f32x4_t lo = *(const f32x4_t*)(xr + (((g * 2)     ^ (r15 & 7)) * 16));
    f32x4_t hi = *(const f32x4_t*)(xr + (((g * 2 + 1) ^ (r15 & 7)) * 16));
    bf16x8_t af;
    af[0] = (__bf16)lo[0]; af[1] = (__bf16)lo[1];
    af[2] = (__bf16)lo[2]; af[3] = (__bf16)lo[3];
    af[4] = (__bf16)hi[0]; af[5] = (__bf16)hi[1];
    af[6] = (__bf16)hi[2]; af[7] = (__bf16)hi[3];
    s0 += lo[0]*w0[0] + lo[1]*w0[1] + lo[2]*w0[2] + lo[3]*w0[3]
        + hi[0]*w1[0] + hi[1]*w1[1] + hi[2]*w1[2] + hi[3]*w1[3];
    #pragma unroll
    for (int nf = 0; nf < 8; ++nf) {
      bf16x8_t bfr = *(const bf16x8_t*)(wbp + (nf * 64 + lane) * 16);
      acc[nf] = __builtin_amdgcn_mfma_f32_16x16x32_bf16(af, bfr, acc[nf], 0, 0, 0);
    }
  };

  // prologue: W(0), X(0), X(1)  -> 6 loads/wave outstanding
  STAGE_W(0);
  STAGE_X(0, 0);
  STAGE_X(1, 1);

  int xb = 0;                                      // buffer of tile `it` (it % 3)
  for (int it = 0; it < 63; ++it) {
    // all but newest 2 (X(it+1)) complete => W(it), X(it) resident
    asm volatile("s_waitcnt vmcnt(2)" ::: "memory");
    __builtin_amdgcn_s_barrier();
    __builtin_amdgcn_sched_barrier(0);
    STAGE_W(it + 1);                               // buf (it+1)&1, freed by barrier
    if (it < 62) {
      int b2 = xb + 2; if (b2 >= 3) b2 -= 3;
      STAGE_X(it + 2, b2);                         // buf (it+2)%3, freed by barrier
    }
    COMPUTE(it, xb);
    ++xb; if (xb == 3) xb = 0;
  }
  // peeled last step: only W(63) (+maybe X(63)) outstanding -> full drain
  asm volatile("s_waitcnt vmcnt(0)" ::: "memory");
  __builtin_amdgcn_s_barrier();
  __builtin_amdgcn_sched_barrier(0);
  COMPUTE(63, xb);

  // s0: combine the 4 k-groups of each row (lanes differing in bits 4,5)
  s0 += __shfl_xor(s0, 16, 64);
  s0 += __shfl_xor(s0, 32, 64);

  // epilogue: C col=lane&15, row=g*4+reg; a-frag nf pairs with b-frag nf+4
  #pragma unroll
  for (int r = 0; r < 4; ++r) {
    float v = 0.f;
    #pragma unroll
    for (int nf = 0; nf < 4; ++nf) {
      float av = acc[nf][r];
      float bv = acc[nf + 4][r];
      v += av / (1.f + __expf(-bv));          // a * sigmoid(b)
    }
    v += __shfl_xor(v, 1, 64);
    v += __shfl_xor(v, 2, 64);
    v += __shfl_xor(v, 4, 64);
    v += __shfl_xor(v, 8, 64);
    const int row = g * 4 + r;
    float s0r = __shfl(s0, row, 64);          // s0 lives at lane with r15==row
    if (r15 == 0) out[tile + wv * 16 + row] = v + s0r;
  }
}

extern "C" void kernel_launch(void* const* d_in, const int* in_sizes, int n_in,
                              void* d_out, int out_size, void* d_ws, size_t ws_size,
                              hipStream_t stream) {
  const float* x    = (const float*)d_in[0];
  const float* wqkv = (const float*)d_in[1];
  const float* wz   = (const float*)d_in[2];
  const float* wb   = (const float*)d_in[3];   // dict order: w_b before w_a
  const float* wa   = (const float*)d_in[4];
  float* out = (float*)d_out;

  float* partial = (float*)d_ws;                                      // 1 MB
  float* wsum = (float*)((char*)d_ws + (1 << 20));                    // 8 KB
  unsigned short* wbf3 = (unsigned short*)((char*)d_ws + (1 << 20) + 8192); // 512 KB

  k_prep1<<<128, 256, 0, stream>>>(wqkv, wz, partial);
  k_wsum2<<<8, 256, 0, stream>>>(partial, wsum);
  k_prep2<<<128, 256, 0, stream>>>(wb, wa, wbf3);
  k_main<<<out_size / 64, 256, 0, stream>>>(x, wbf3, wsum, out);
}

// Round 7
// 58.843 us; speedup vs baseline: 1.5592x; 1.1176x over previous
//
#include <hip/hip_runtime.h>
#include <stdint.h>

using bf16x8_t = __attribute__((ext_vector_type(8))) __bf16;
using f32x4_t  = __attribute__((ext_vector_type(4))) float;
using u16x8_t  = __attribute__((ext_vector_type(8))) unsigned short;

#define KD 2048

static __device__ __forceinline__ unsigned short f2bf(float f) {
  union { float f; unsigned u; } v; v.f = f;
  unsigned r = v.u + 0x7fffu + ((v.u >> 16) & 1u);   // RNE
  return (unsigned short)(r >> 16);
}

// ---- single fused prep ----
// blocks 0..127:   pack 8-fragment bf16 W. elem ((s*8+nf)*64+lane)*8+j  <->
//                  B[col=nf*16+(lane&15)][k=s*32+(lane>>4)*8+j]; cols 0..63=w_a,
//                  64..127=w_b.
// blocks 128..383: wsum[h] = sum_d wqkv[d][h] + sum_d wz[d][h], 8 cols/block,
//                  fixed-tree reduction (deterministic).
__global__ void k_prep(const float* __restrict__ wqkv, const float* __restrict__ wz,
                       const float* __restrict__ wb, const float* __restrict__ wa,
                       float* __restrict__ wsum, unsigned short* __restrict__ wbf3) {
  __shared__ float red[4][8];
  const int b = blockIdx.x, t = threadIdx.x;
  if (b < 128) {
    const int u = b * 256 + t;                   // 32768 threads x 8 shorts
    const int l = u & 63;
    const int vv = u >> 6;
    const int nf = vv & 7;
    const int s  = vv >> 3;
    const int k  = s * 32 + ((l >> 4) << 3);
    const int c  = nf * 16 + (l & 15);
    const float* src = (c < 64) ? (wa + (size_t)c * KD + k)
                                : (wb + (size_t)(c - 64) * KD + k);
    f32x4_t v0 = *(const f32x4_t*)(src);
    f32x4_t v1 = *(const f32x4_t*)(src + 4);
    u16x8_t o;
    o[0]=f2bf(v0[0]); o[1]=f2bf(v0[1]); o[2]=f2bf(v0[2]); o[3]=f2bf(v0[3]);
    o[4]=f2bf(v1[0]); o[5]=f2bf(v1[1]); o[6]=f2bf(v1[2]); o[7]=f2bf(v1[3]);
    *(u16x8_t*)(wbf3 + (size_t)u * 8) = o;
  } else {
    const int bw = b - 128;                      // 0..255, cols bw*8..bw*8+7
    const int c = t & 7;
    const int rg = t >> 3;                       // 0..31
    const int h = bw * 8 + c;
    float s = 0.f;
    #pragma unroll 8
    for (int i = 0; i < 40; ++i) {
      const int r = rg + 32 * i;                 // 0..1279
      const float* p = (r < 768) ? (wqkv + (size_t)r * KD)
                                 : (wz + (size_t)(r - 768) * KD);
      s += p[h];
    }
    // lane = ((rg&7)<<3)|c within wave; fold rg bits (lane bits 3,4,5)
    s += __shfl_xor(s, 8, 64);
    s += __shfl_xor(s, 16, 64);
    s += __shfl_xor(s, 32, 64);
    const int lane = t & 63, wv = t >> 6;
    if (lane < 8) red[wv][lane] = s;
    __syncthreads();
    if (t < 8) wsum[bw * 8 + t] = red[0][t] + red[1][t] + red[2][t] + red[3][t];
  }
}

// ---- main: BM=64 (4 waves x 16 rows), BK=32, 64 K-steps.
// Counted-vmcnt pipeline (T3/T4): X triple-buffered (2-iter latency cover),
// W double-buffered (1-iter). Raw s_barrier + s_waitcnt vmcnt(2) -> loads
// never drain to 0 in the main loop. LDS: 3x8K X | 2x8K W | 8K wsum = 48 KB
// -> 3 blocks/CU (144/160 KB). X chunks wave-private.
__global__ __launch_bounds__(256, 3) void k_main(
    const float* __restrict__ x, const unsigned short* __restrict__ wbf3,
    const float* __restrict__ wsum, float* __restrict__ out)
{
  __shared__ __align__(16) unsigned char lds[49152];
  float* swb = (float*)(lds + 40960);
  const int t = threadIdx.x;
  const int lane = t & 63;
  const int wv = t >> 6;
  const int g = lane >> 4;        // k-group 0..3
  const int r15 = lane & 15;
  const size_t tile = (size_t)blockIdx.x * 64;

  // one-time: wsum -> LDS (fp32, 8 KB)
  {
    f32x4_t a = *(const f32x4_t*)(wsum + t * 8);
    f32x4_t b = *(const f32x4_t*)(wsum + t * 8 + 4);
    *(f32x4_t*)(swb + t * 8) = a;
    *(f32x4_t*)(swb + t * 8 + 4) = b;
  }
  __syncthreads();   // wsum visible; vmcnt drained -> clean counting below

  f32x4_t acc[8];
  #pragma unroll
  for (int i = 0; i < 8; ++i) acc[i] = f32x4_t{0.f, 0.f, 0.f, 0.f};
  float s0 = 0.f;

  // W stage: 8 chunks of 1KB; wave wv takes chunks wv*2, wv*2+1 (2 vmcnt units)
  auto STAGE_W = [&](int it) {
    unsigned char* wbp = lds + 24576 + (it & 1) * 8192;
    const unsigned short* gw = wbf3 + (size_t)it * 4096 + lane * 8;
    #pragma unroll
    for (int i = 0; i < 2; ++i) {
      const int ch = wv * 2 + i;
      __builtin_amdgcn_global_load_lds(
          (const __attribute__((address_space(1))) void*)(gw + ch * 512),
          (__attribute__((address_space(3))) void*)(wbp + ch * 1024), 16, 0, 0);
    }
  };
  // X stage: 8 chunks of 1KB (8 rows x 128B); wave-private rows.
  // LDS[row][slot] holds global slot (slot ^ (row&7))  (XOR swizzle).
  auto STAGE_X = [&](int it, int bsel) {
    unsigned char* xbp = lds + bsel * 8192;
    #pragma unroll
    for (int i = 0; i < 2; ++i) {
      const int ch = wv * 2 + i;
      const int r = ch * 8 + (lane >> 3);          // row within tile
      const int c = (lane & 7) ^ (r & 7);          // source 16B slot
      const float* src = x + (tile + r) * KD + it * 32 + c * 4;
      __builtin_amdgcn_global_load_lds(
          (const __attribute__((address_space(1))) void*)src,
          (__attribute__((address_space(3))) void*)(xbp + ch * 1024), 16, 0, 0);
    }
  };
  auto COMPUTE = [&](int it, int xbsel) {
    const unsigned char* xbp = lds + xbsel * 8192;
    const unsigned char* wbp = lds + 24576 + (it & 1) * 8192;
    const float* wsp = swb + it * 32 + g * 8;      // LDS broadcast
    f32x4_t w0 = *(const f32x4_t*)(wsp);
    f32x4_t w1 = *(const f32x4_t*)(wsp + 4);
    const int r = wv * 16 + r15;
    const unsigned char* xr = xbp + r * 128;
    f32x4_t lo = *(const f32x4_t*)(xr + (((g * 2)     ^ (r15 & 7)) * 16));
    f32x4_t hi = *(const f32x4_t*)(xr + (((g * 2 + 1) ^ (r15 & 7)) * 16));
    bf16x8_t af;
    af[0] = (__bf16)lo[0]; af[1] = (__bf16)lo[1];
    af[2] = (__bf16)lo[2]; af[3] = (__bf16)lo[3];
    af[4] = (__bf16)hi[0]; af[5] = (__bf16)hi[1];
    af[6] = (__bf16)hi[2]; af[7] = (__bf16)hi[3];
    s0 += lo[0]*w0[0] + lo[1]*w0[1] + lo[2]*w0[2] + lo[3]*w0[3]
        + hi[0]*w1[0] + hi[1]*w1[1] + hi[2]*w1[2] + hi[3]*w1[3];
    #pragma unroll
    for (int nf = 0; nf < 8; ++nf) {
      bf16x8_t bfr = *(const bf16x8_t*)(wbp + (nf * 64 + lane) * 16);
      acc[nf] = __builtin_amdgcn_mfma_f32_16x16x32_bf16(af, bfr, acc[nf], 0, 0, 0);
    }
  };

  // prologue: W(0), X(0), X(1)  -> 6 loads/wave outstanding
  STAGE_W(0);
  STAGE_X(0, 0);
  STAGE_X(1, 1);

  int xb = 0;                                      // buffer of tile `it` (it % 3)
  for (int it = 0; it < 63; ++it) {
    // all but newest 2 (X(it+1)) complete => W(it), X(it) resident
    asm volatile("s_waitcnt vmcnt(2)" ::: "memory");
    __builtin_amdgcn_s_barrier();
    __builtin_amdgcn_sched_barrier(0);
    STAGE_W(it + 1);                               // buf (it+1)&1, freed by barrier
    if (it < 62) {
      int b2 = xb + 2; if (b2 >= 3) b2 -= 3;
      STAGE_X(it + 2, b2);                         // buf (it+2)%3, freed by barrier
    }
    COMPUTE(it, xb);
    ++xb; if (xb == 3) xb = 0;
  }
  // peeled last step: full drain
  asm volatile("s_waitcnt vmcnt(0)" ::: "memory");
  __builtin_amdgcn_s_barrier();
  __builtin_amdgcn_sched_barrier(0);
  COMPUTE(63, xb);

  // s0: combine the 4 k-groups of each row (lanes differing in bits 4,5)
  s0 += __shfl_xor(s0, 16, 64);
  s0 += __shfl_xor(s0, 32, 64);

  // epilogue: C col=lane&15, row=g*4+reg; a-frag nf pairs with b-frag nf+4
  #pragma unroll
  for (int r = 0; r < 4; ++r) {
    float v = 0.f;
    #pragma unroll
    for (int nf = 0; nf < 4; ++nf) {
      float av = acc[nf][r];
      float bv = acc[nf + 4][r];
      v += av / (1.f + __expf(-bv));          // a * sigmoid(b)
    }
    v += __shfl_xor(v, 1, 64);
    v += __shfl_xor(v, 2, 64);
    v += __shfl_xor(v, 4, 64);
    v += __shfl_xor(v, 8, 64);
    const int row = g * 4 + r;
    float s0r = __shfl(s0, row, 64);          // s0 lives at lane with r15==row
    if (r15 == 0) out[tile + wv * 16 + row] = v + s0r;
  }
}

extern "C" void kernel_launch(void* const* d_in, const int* in_sizes, int n_in,
                              void* d_out, int out_size, void* d_ws, size_t ws_size,
                              hipStream_t stream) {
  const float* x    = (const float*)d_in[0];
  const float* wqkv = (const float*)d_in[1];
  const float* wz   = (const float*)d_in[2];
  const float* wb   = (const float*)d_in[3];   // dict order: w_b before w_a
  const float* wa   = (const float*)d_in[4];
  float* out = (float*)d_out;

  float* wsum = (float*)d_ws;                                   // 8 KB
  unsigned short* wbf3 = (unsigned short*)((char*)d_ws + 8192); // 512 KB pre-fragmented W

  k_prep<<<384, 256, 0, stream>>>(wqkv, wz, wb, wa, wsum, wbf3);
  k_main<<<out_size / 64, 256, 0, stream>>>(x, wbf3, wsum, out);
}